// Round 6
// baseline (63.933 us; speedup 1.0000x reference)
//
#include <hip/hip_runtime.h>
#include <hip/hip_bf16.h>
#include <cstdint>

#define SIGMA 0.01f

constexpr int D1 = 3072;
constexpr int D2 = 2048;
constexpr int D3 = 1024;

typedef __bf16 bf16x8 __attribute__((ext_vector_type(8)));
typedef float f32x4 __attribute__((ext_vector_type(4)));

#define GLOAD16(gp, lp) \
  __builtin_amdgcn_global_load_lds((const __attribute__((address_space(1))) void*)(gp), \
                                   (__attribute__((address_space(3))) void*)(lp), 16, 0, 0)

// ---------- K1: bias add + 2x2 avgpool + per-block partial sum(pooled^2) ----------
__global__ void pool_kernel(const float* __restrict__ x, const float* __restrict__ bias,
                            float* __restrict__ pooled, float* __restrict__ Spart) {
  int idx = blockIdx.x * 256 + threadIdx.x;   // [0, 4*3072)
  int b = idx / D1;
  int r = idx % D1;
  int c = r >> 10;
  int oh = (r >> 5) & 31;
  int ow = r & 31;
  int xb = ((b * 3 + c) * 64 + oh * 2) * 64 + ow * 2;
  int bb = (c * 64 + oh * 2) * 64 + ow * 2;
  float v = 0.25f * ((x[xb] + bias[bb]) + (x[xb + 1] + bias[bb + 1]) +
                     (x[xb + 64] + bias[bb + 64]) + (x[xb + 65] + bias[bb + 65]));
  pooled[idx] = v;
  float s = v * v;
  #pragma unroll
  for (int off = 32; off; off >>= 1) s += __shfl_down(s, off, 64);
  __shared__ float wsum[4];
  if ((threadIdx.x & 63) == 0) wsum[threadIdx.x >> 6] = s;
  __syncthreads();
  if (threadIdx.x == 0) Spart[blockIdx.x] = wsum[0] + wsum[1] + wsum[2] + wsum[3];
}

// ---------- K2: mu=pooled@W1^T (+activation moments), 2 rows/block ----------
__global__ void lin1_kernel(const float* __restrict__ pooled, const float* __restrict__ W1,
                            const float* __restrict__ Spart, const float* __restrict__ g1p,
                            float* __restrict__ musp, float* __restrict__ dscale,
                            float* __restrict__ m2b, float* __restrict__ Pp1) {
  int o2 = blockIdx.x << 1, tid = threadIdx.x;
  const float4* w0p = (const float4*)(W1 + (size_t)o2 * D1);
  const float4* w1p = (const float4*)(W1 + (size_t)(o2 + 1) * D1);
  const float4* p4 = (const float4*)pooled;
  float a0[4] = {0,0,0,0}, q0[4] = {0,0,0,0}, a1[4] = {0,0,0,0}, q1[4] = {0,0,0,0};
  #pragma unroll
  for (int it = 0; it < 3; it++) {
    int i4 = tid + it * 256;
    float4 w0 = w0p[i4], w1 = w1p[i4];
    float x0x = fabsf(w0.x), x0y = fabsf(w0.y), x0z = fabsf(w0.z), x0w = fabsf(w0.w);
    float x1x = fabsf(w1.x), x1y = fabsf(w1.y), x1z = fabsf(w1.z), x1w = fabsf(w1.w);
    #pragma unroll
    for (int b = 0; b < 4; b++) {
      float4 p = p4[b * 768 + i4];
      float px = p.x * p.x, py = p.y * p.y, pz = p.z * p.z, pw = p.w * p.w;
      a0[b] += w0.x * p.x + w0.y * p.y + w0.z * p.z + w0.w * p.w;
      q0[b] += x0x * px + x0y * py + x0z * pz + x0w * pw;
      a1[b] += w1.x * p.x + w1.y * p.y + w1.z * p.z + w1.w * p.w;
      q1[b] += x1x * px + x1y * py + x1z * pz + x1w * pw;
    }
  }
  __shared__ float red[16][4];
  #pragma unroll
  for (int v = 0; v < 16; v++) {
    float s = (v < 4) ? a0[v] : (v < 8) ? q0[v - 4] : (v < 12) ? a1[v - 8] : q1[v - 12];
    #pragma unroll
    for (int off = 32; off; off >>= 1) s += __shfl_down(s, off, 64);
    if ((tid & 63) == 0) red[v][tid >> 6] = s;
  }
  __syncthreads();
  if (tid < 16) {
    float s = red[tid][0] + red[tid][1] + red[tid][2] + red[tid][3];
    int rr = tid >> 3, u = tid & 7;
    int o = o2 + rr;
    if (u < 4) {
      int b = u;
      float ss = 0.f;
      #pragma unroll
      for (int i = 0; i < 12; i++) ss += Spart[b * 12 + i];
      float c1 = g1p[0];
      float vn1 = 2.0f * (SIGMA / c1) * (SIGMA / c1) * ss;
      float d = 1.0f / (1.0f + expf(-s));
      float sp = fmaxf(s, 0.f) + log1pf(expf(-fabsf(s)));
      musp[b * D2 + o] = sp;
      dscale[b * D2 + o] = sqrtf(vn1) * d;
      m2b[b * D2 + o] = sp * sp + vn1 * d * d;
    } else {
      Pp1[(size_t)(u - 4) * D2 + o] = s;
    }
  }
}

// ---------- K3: E = bf16(W2 * dscale); mu2 = musp @ W2^T; Pp2 partials (2 rows/block) ----------
__global__ void lin2_prep_kernel(const float* __restrict__ W2, const float* __restrict__ musp,
                                 const float* __restrict__ dscale, const float* __restrict__ m2b,
                                 __bf16* __restrict__ E, float* __restrict__ mu2,
                                 float* __restrict__ Pp2) {
  int o2 = blockIdx.x << 1, tid = threadIdx.x;
  int j0 = tid * 8;
  float w0[8], w1[8];
  *(float4*)&w0[0] = *(const float4*)(W2 + (size_t)o2 * D2 + j0);
  *(float4*)&w0[4] = *(const float4*)(W2 + (size_t)o2 * D2 + j0 + 4);
  *(float4*)&w1[0] = *(const float4*)(W2 + (size_t)(o2 + 1) * D2 + j0);
  *(float4*)&w1[4] = *(const float4*)(W2 + (size_t)(o2 + 1) * D2 + j0 + 4);
  float a0[4], q0[4], a1[4], q1[4];
  #pragma unroll
  for (int b = 0; b < 4; b++) {
    const float* ms = musp + b * D2 + j0;
    const float* dsc = dscale + b * D2 + j0;
    const float* mb = m2b + b * D2 + j0;
    bf16x8 e0, e1;
    float s0 = 0.f, p0 = 0.f, s1 = 0.f, p1 = 0.f;
    #pragma unroll
    for (int jj = 0; jj < 8; jj++) {
      float dv = dsc[jj], mv = ms[jj], bv = mb[jj];
      e0[jj] = (__bf16)(w0[jj] * dv);
      e1[jj] = (__bf16)(w1[jj] * dv);
      s0 += w0[jj] * mv;  p0 += fabsf(w0[jj]) * bv;
      s1 += w1[jj] * mv;  p1 += fabsf(w1[jj]) * bv;
    }
    *(bf16x8*)(E + ((size_t)b * D3 + o2) * D2 + j0) = e0;
    *(bf16x8*)(E + ((size_t)b * D3 + o2 + 1) * D2 + j0) = e1;
    a0[b] = s0; q0[b] = p0; a1[b] = s1; q1[b] = p1;
  }
  __shared__ float red[16][4];
  #pragma unroll
  for (int v = 0; v < 16; v++) {
    float s = (v < 4) ? a0[v] : (v < 8) ? q0[v - 4] : (v < 12) ? a1[v - 8] : q1[v - 12];
    #pragma unroll
    for (int off = 32; off; off >>= 1) s += __shfl_down(s, off, 64);
    if ((tid & 63) == 0) red[v][tid >> 6] = s;
  }
  __syncthreads();
  if (tid < 16) {
    float s = red[tid][0] + red[tid][1] + red[tid][2] + red[tid][3];
    int rr = tid >> 3, u = tid & 7;
    int o = o2 + rr;
    if (u < 4) mu2[u * D3 + o] = s;
    else Pp2[(size_t)(u - 4) * D3 + o] = s;
  }
}

// ---------- K4: gamma2[b] = E_b E_b^T + vn2 I ; vn2 + Ptot in epilogue ----------
// Upper-triangular 64x64 tiles (136/batch, 544 blocks); mirror-write lower half.
// 4-buffer LDS pipeline, 2 tiles in flight, counted vmcnt(8), raw s_barrier.
__global__ __launch_bounds__(256, 2) void gamma2_gemm(const __bf16* __restrict__ E,
                                                      const float* __restrict__ m2b,
                                                      const float* __restrict__ Pp1,
                                                      const float* __restrict__ Pp2,
                                                      const float* __restrict__ g1p,
                                                      const float* __restrict__ g2p,
                                                      float* __restrict__ gamma2,
                                                      float* __restrict__ Ptot) {
  int bid = blockIdx.x, tid = threadIdx.x;
  int wid = tid >> 6, lane = tid & 63;
  int wr = wid >> 1, wc = wid & 1;

  // XCD-pinned decode: 544 blocks (544%8==0), batch b = xcd>>1.
  int xcd = bid & 7, r = bid >> 3;          // r in [0,68)
  int b = xcd >> 1;
  int t = (r << 1) | (xcd & 1);             // [0,136) tile id within batch
  int s = 135 - t;
  int k = (int)((sqrtf((float)(8 * s + 1)) - 1.0f) * 0.5f);
  while ((k + 1) * (k + 2) / 2 <= s) k++;
  while (k * (k + 1) / 2 > s) k--;
  int i = s - k * (k + 1) / 2;
  int tm = 15 - k, tn = 15 - i;

  __shared__ __bf16 As[4][4096], Bs[4][4096];   // 64 KB total
  char* AsB = (char*)As;
  char* BsB = (char*)Bs;

  const __bf16* Eb = E + (size_t)b * D3 * D2;
  int rb0 = wid >> 1, ks0 = wid & 1;          // region wid
  int rb1 = (wid + 4) >> 1;                   // region wid+4 (same k-half)
  int srow = lane >> 2, skc = lane & 3;
  const __bf16* gA0 = Eb + (size_t)(tm * 64 + rb0 * 16 + srow) * D2 + ks0 * 32 + skc * 8;
  const __bf16* gA1 = Eb + (size_t)(tm * 64 + rb1 * 16 + srow) * D2 + ks0 * 32 + skc * 8;
  const __bf16* gB0 = Eb + (size_t)(tn * 64 + rb0 * 16 + srow) * D2 + ks0 * 32 + skc * 8;
  const __bf16* gB1 = Eb + (size_t)(tn * 64 + rb1 * 16 + srow) * D2 + ks0 * 32 + skc * 8;
  unsigned dst0 = (unsigned)wid * 1024u;          // HW adds lane*16
  unsigned dst1 = dst0 + 4096u;

  int fr = lane & 15, kg = lane >> 4;
  unsigned po = (unsigned)(fr * 64 + kg * 16);
  unsigned aM0 = (unsigned)(wr * 4096) + po;
  unsigned aM1 = aM0 + 2048u;
  unsigned bN0 = (unsigned)(wc * 4096) + po;
  unsigned bN1 = bN0 + 2048u;

  f32x4 acc[2][2] = {};

#define STAGE(bufoff, kelem)                                   \
  {                                                            \
    GLOAD16(gA0 + (kelem), AsB + (bufoff) + dst0);             \
    GLOAD16(gA1 + (kelem), AsB + (bufoff) + dst1);             \
    GLOAD16(gB0 + (kelem), BsB + (bufoff) + dst0);             \
    GLOAD16(gB1 + (kelem), BsB + (bufoff) + dst1);             \
  }

#define COMPUTE(bufoff)                                                         \
  {                                                                             \
    _Pragma("unroll")                                                           \
    for (int ks2 = 0; ks2 < 2; ks2++) {                                         \
      unsigned kso = (unsigned)ks2 << 10;                                       \
      bf16x8 a0 = *(const bf16x8*)(AsB + (bufoff) + aM0 + kso);                 \
      bf16x8 a1 = *(const bf16x8*)(AsB + (bufoff) + aM1 + kso);                 \
      bf16x8 b0 = *(const bf16x8*)(BsB + (bufoff) + bN0 + kso);                 \
      bf16x8 b1 = *(const bf16x8*)(BsB + (bufoff) + bN1 + kso);                 \
      acc[0][0] = __builtin_amdgcn_mfma_f32_16x16x32_bf16(a0, b0, acc[0][0], 0, 0, 0); \
      acc[0][1] = __builtin_amdgcn_mfma_f32_16x16x32_bf16(a0, b1, acc[0][1], 0, 0, 0); \
      acc[1][0] = __builtin_amdgcn_mfma_f32_16x16x32_bf16(a1, b0, acc[1][0], 0, 0, 0); \
      acc[1][1] = __builtin_amdgcn_mfma_f32_16x16x32_bf16(a1, b1, acc[1][1], 0, 0, 0); \
    }                                                                           \
  }

  // prologue: 2 tiles in flight
  STAGE(0u, 0);
  STAGE(8192u, 64);
  #pragma unroll 1
  for (int kt = 0; kt < 30; kt++) {
    unsigned sb = (unsigned)((kt + 2) & 3) * 8192u;
    STAGE(sb, (kt + 2) * 64);
    asm volatile("s_waitcnt vmcnt(8)" ::: "memory");   // oldest tile's 4 loads done
    __builtin_amdgcn_s_barrier();                      // all waves -> buf[kt] complete
    __builtin_amdgcn_sched_barrier(0);
    COMPUTE((unsigned)(kt & 3) * 8192u);
  }
  asm volatile("s_waitcnt vmcnt(4)" ::: "memory");
  __builtin_amdgcn_s_barrier();
  __builtin_amdgcn_sched_barrier(0);
  COMPUTE((unsigned)(30 & 3) * 8192u);
  asm volatile("s_waitcnt vmcnt(0)" ::: "memory");
  __builtin_amdgcn_s_barrier();
  __builtin_amdgcn_sched_barrier(0);
  COMPUTE((unsigned)(31 & 3) * 8192u);
#undef STAGE
#undef COMPUTE

  // epilogue scalars: vn2 (per-wave full reduce of m2b[b,:], all lanes get sum)
  float c2 = g2p[0];
  float sm = 0.f;
  #pragma unroll
  for (int ii = 0; ii < 32; ii++) sm += m2b[(size_t)b * D2 + lane + ii * 64];
  #pragma unroll
  for (int off = 32; off; off >>= 1) sm += __shfl_xor(sm, off, 64);
  float vn2 = 2.0f * (SIGMA / c2) * (SIGMA / c2) * sm;

  // blocks 0..3, wave 0: finalize Ptot[bid]
  if (bid < 4 && wid == 0) {
    float s1 = 0.f, s2 = 0.f;
    #pragma unroll
    for (int ii = 0; ii < 32; ii++) s1 += Pp1[(size_t)bid * D2 + lane + ii * 64];
    #pragma unroll
    for (int ii = 0; ii < 16; ii++) s2 += Pp2[(size_t)bid * D3 + lane + ii * 64];
    #pragma unroll
    for (int off = 32; off; off >>= 1) {
      s1 += __shfl_down(s1, off, 64);
      s2 += __shfl_down(s2, off, 64);
    }
    if (lane == 0) Ptot[bid] = g1p[0] * s1 + c2 * s2;
  }

  float* outb = gamma2 + (size_t)b * D3 * D3;
  int row0 = tm * 64 + wr * 32 + kg * 4;
  int col0 = tn * 64 + wc * 32 + fr;
  #pragma unroll
  for (int mi = 0; mi < 2; mi++)
    #pragma unroll
    for (int ni = 0; ni < 2; ni++)
      #pragma unroll
      for (int rg = 0; rg < 4; rg++) {
        int row = row0 + mi * 16 + rg;
        int cc = col0 + ni * 16;
        float v = acc[mi][ni][rg];
        if (row == cc) v += vn2;
        outb[(size_t)row * D3 + cc] = v;
      }
  if (tm != tn) {
    #pragma unroll
    for (int mi = 0; mi < 2; mi++)
      #pragma unroll
      for (int ni = 0; ni < 2; ni++) {
        int cc = col0 + ni * 16;
        int rowb = row0 + mi * 16;
        *(f32x4*)(outb + (size_t)cc * D3 + rowb) = acc[mi][ni];
      }
  }
}

extern "C" void kernel_launch(void* const* d_in, const int* in_sizes, int n_in,
                              void* d_out, int out_size, void* d_ws, size_t ws_size,
                              hipStream_t stream) {
  (void)in_sizes; (void)n_in; (void)out_size; (void)ws_size;
  const float* x    = (const float*)d_in[0];
  const float* bias = (const float*)d_in[1];
  const float* W1   = (const float*)d_in[2];
  const float* W2   = (const float*)d_in[3];
  const float* g1   = (const float*)d_in[4];
  const float* g2   = (const float*)d_in[5];
  float* out = (float*)d_out;

  float* ws     = (float*)d_ws;
  float* pooled = ws;                    // 4*3072
  float* musp   = pooled + 4 * D1;       // 4*2048
  float* dscale = musp + 4 * D2;         // 4*2048
  float* m2b    = dscale + 4 * D2;       // 4*2048
  float* Pp1    = m2b + 4 * D2;          // 4*2048
  float* Pp2    = Pp1 + 4 * D2;          // 4*1024
  float* Spart  = Pp2 + 4 * D3;          // 48
  size_t used = (size_t)(4 * D1 + 4 * 4 * D2 + 4 * D3 + 64) * 4;
  size_t eoff = (used + 255) / 256 * 256;
  __bf16* E = (__bf16*)((char*)d_ws + eoff);   // 4*1024*2048 bf16 = 16 MiB

  float* mu2_out  = out;
  float* gam_out  = out + 4 * D3;
  float* ptot_out = out + 4 * D3 + (size_t)4 * D3 * D3;

  pool_kernel<<<48, 256, 0, stream>>>(x, bias, pooled, Spart);
  lin1_kernel<<<1024, 256, 0, stream>>>(pooled, W1, Spart, g1, musp, dscale, m2b, Pp1);
  lin2_prep_kernel<<<512, 256, 0, stream>>>(W2, musp, dscale, m2b, E, mu2_out, Pp2);
  gamma2_gemm<<<544, 256, 0, stream>>>(E, m2b, Pp1, Pp2, g1, g2, gam_out, ptot_out);
}

// Round 7
// 60.557 us; speedup vs baseline: 1.0557x; 1.0557x over previous
//
#include <hip/hip_runtime.h>
#include <hip/hip_bf16.h>
#include <cstdint>

#define SIGMA 0.01f

constexpr int D1 = 3072;
constexpr int D2 = 2048;
constexpr int D3 = 1024;

typedef __bf16 bf16x8 __attribute__((ext_vector_type(8)));
typedef float f32x4 __attribute__((ext_vector_type(4)));

#define GLOAD16(gp, lp) \
  __builtin_amdgcn_global_load_lds((const __attribute__((address_space(1))) void*)(gp), \
                                   (__attribute__((address_space(3))) void*)(lp), 16, 0, 0)

// ---------- K1: fused pool + lin1 (+activation moments), 4 W1 rows/block ----------
// Each block recomputes the full pooled[4][3072] into LDS (x is L2/L3-hot),
// giving the complete Ssum locally -> no pool node, no Spart round-trip.
__global__ __launch_bounds__(256) void lin1_fused(const float* __restrict__ x,
                                                  const float* __restrict__ bias,
                                                  const float* __restrict__ W1,
                                                  const float* __restrict__ g1p,
                                                  float* __restrict__ musp,
                                                  float* __restrict__ dscale,
                                                  float* __restrict__ m2b,
                                                  float* __restrict__ Pp1) {
  __shared__ float pooled_s[12288];   // 48 KB
  __shared__ float sred[4][4];
  __shared__ float Ssum_s[4];
  __shared__ float red[32][4];
  int tid = threadIdx.x;

  // Phase A: pool into LDS. Each thread: 24 pairs (2 outputs via float4 rows).
  float sacc[4] = {0, 0, 0, 0};
  #pragma unroll
  for (int it = 0; it < 24; it++) {
    int b = it / 6;                       // compile-time (full unroll)
    int lp = (it % 6) * 256 + tid;        // pair idx within batch [0,1536)
    int r = lp * 2;                       // even local output idx [0,3072)
    int c = r >> 10, oh = (r >> 5) & 31, ow = r & 31;
    int xb = ((b * 3 + c) * 64 + oh * 2) * 64 + ow * 2;
    int bb = (c * 64 + oh * 2) * 64 + ow * 2;
    float4 x0 = *(const float4*)(x + xb);
    float4 x1 = *(const float4*)(x + xb + 64);
    float4 b0 = *(const float4*)(bias + bb);
    float4 b1 = *(const float4*)(bias + bb + 64);
    float v0 = 0.25f * ((x0.x + b0.x) + (x0.y + b0.y) + (x1.x + b1.x) + (x1.y + b1.y));
    float v1 = 0.25f * ((x0.z + b0.z) + (x0.w + b0.w) + (x1.z + b1.z) + (x1.w + b1.w));
    *(float2*)(pooled_s + b * 3072 + r) = make_float2(v0, v1);
    sacc[b] += v0 * v0 + v1 * v1;
  }
  #pragma unroll
  for (int v = 0; v < 4; v++) {
    float sv = sacc[v];
    #pragma unroll
    for (int off = 32; off; off >>= 1) sv += __shfl_down(sv, off, 64);
    if ((tid & 63) == 0) sred[v][tid >> 6] = sv;
  }
  __syncthreads();
  if (tid < 4) Ssum_s[tid] = sred[tid][0] + sred[tid][1] + sred[tid][2] + sred[tid][3];
  __syncthreads();

  // Phase B: 4 W1 rows, mu + power partials vs all 4 batches.
  int o4 = blockIdx.x << 2;
  const float4* w0p = (const float4*)(W1 + (size_t)(o4 + 0) * D1);
  const float4* w1p = (const float4*)(W1 + (size_t)(o4 + 1) * D1);
  const float4* w2p = (const float4*)(W1 + (size_t)(o4 + 2) * D1);
  const float4* w3p = (const float4*)(W1 + (size_t)(o4 + 3) * D1);
  const float4* p4 = (const float4*)pooled_s;
  float a[4][4] = {}, q[4][4] = {};
  #pragma unroll
  for (int it = 0; it < 3; it++) {
    int i4 = tid + it * 256;
    float4 w[4];
    w[0] = w0p[i4]; w[1] = w1p[i4]; w[2] = w2p[i4]; w[3] = w3p[i4];
    #pragma unroll
    for (int b = 0; b < 4; b++) {
      float4 p = p4[b * 768 + i4];
      float px = p.x * p.x, py = p.y * p.y, pz = p.z * p.z, pw = p.w * p.w;
      #pragma unroll
      for (int rr = 0; rr < 4; rr++) {
        a[rr][b] += w[rr].x * p.x + w[rr].y * p.y + w[rr].z * p.z + w[rr].w * p.w;
        q[rr][b] += fabsf(w[rr].x) * px + fabsf(w[rr].y) * py +
                    fabsf(w[rr].z) * pz + fabsf(w[rr].w) * pw;
      }
    }
  }
  #pragma unroll
  for (int v = 0; v < 32; v++) {
    float s = (v < 16) ? a[v >> 2][v & 3] : q[(v - 16) >> 2][(v - 16) & 3];
    #pragma unroll
    for (int off = 32; off; off >>= 1) s += __shfl_down(s, off, 64);
    if ((tid & 63) == 0) red[v][tid >> 6] = s;
  }
  __syncthreads();
  if (tid < 32) {
    int rr = tid >> 3, u = tid & 7;
    int idx = (u < 4) ? (rr * 4 + u) : (16 + rr * 4 + (u - 4));
    float s = red[idx][0] + red[idx][1] + red[idx][2] + red[idx][3];
    int o = o4 + rr;
    if (u < 4) {
      int b = u;
      float c1 = g1p[0];
      float vn1 = 2.0f * (SIGMA / c1) * (SIGMA / c1) * Ssum_s[b];
      float d = 1.0f / (1.0f + expf(-s));
      float sp = fmaxf(s, 0.f) + log1pf(expf(-fabsf(s)));
      musp[b * D2 + o] = sp;
      dscale[b * D2 + o] = sqrtf(vn1) * d;
      m2b[b * D2 + o] = sp * sp + vn1 * d * d;
    } else {
      Pp1[(size_t)(u - 4) * D2 + o] = s;
    }
  }
}

// ---------- K2: E = bf16(W2*dscale); mu2; Pp2 partials; blocks 512..515: vn2v ----------
__global__ void lin2_prep_kernel(const float* __restrict__ W2, const float* __restrict__ musp,
                                 const float* __restrict__ dscale, const float* __restrict__ m2b,
                                 const float* __restrict__ g2p, __bf16* __restrict__ E,
                                 float* __restrict__ mu2, float* __restrict__ Pp2,
                                 float* __restrict__ vn2v) {
  int tid = threadIdx.x;
  if (blockIdx.x >= 512) {
    // vn2[b] = 2*(sigma/c2)^2 * sum_j m2b[b][j]
    int b = blockIdx.x - 512;
    float sm = 0.f;
    #pragma unroll
    for (int i = 0; i < 8; i++) sm += m2b[(size_t)b * D2 + tid + i * 256];
    #pragma unroll
    for (int off = 32; off; off >>= 1) sm += __shfl_down(sm, off, 64);
    __shared__ float red1[4];
    if ((tid & 63) == 0) red1[tid >> 6] = sm;
    __syncthreads();
    if (tid == 0) {
      float c2 = g2p[0];
      vn2v[b] = 2.0f * (SIGMA / c2) * (SIGMA / c2) * (red1[0] + red1[1] + red1[2] + red1[3]);
    }
    return;
  }
  int o2 = blockIdx.x << 1;
  int j0 = tid * 8;
  float w0[8], w1[8];
  *(float4*)&w0[0] = *(const float4*)(W2 + (size_t)o2 * D2 + j0);
  *(float4*)&w0[4] = *(const float4*)(W2 + (size_t)o2 * D2 + j0 + 4);
  *(float4*)&w1[0] = *(const float4*)(W2 + (size_t)(o2 + 1) * D2 + j0);
  *(float4*)&w1[4] = *(const float4*)(W2 + (size_t)(o2 + 1) * D2 + j0 + 4);
  float a0[4], q0[4], a1[4], q1[4];
  #pragma unroll
  for (int b = 0; b < 4; b++) {
    const float* ms = musp + b * D2 + j0;
    const float* dsc = dscale + b * D2 + j0;
    const float* mb = m2b + b * D2 + j0;
    bf16x8 e0, e1;
    float s0 = 0.f, p0 = 0.f, s1 = 0.f, p1 = 0.f;
    #pragma unroll
    for (int jj = 0; jj < 8; jj++) {
      float dv = dsc[jj], mv = ms[jj], bv = mb[jj];
      e0[jj] = (__bf16)(w0[jj] * dv);
      e1[jj] = (__bf16)(w1[jj] * dv);
      s0 += w0[jj] * mv;  p0 += fabsf(w0[jj]) * bv;
      s1 += w1[jj] * mv;  p1 += fabsf(w1[jj]) * bv;
    }
    *(bf16x8*)(E + ((size_t)b * D3 + o2) * D2 + j0) = e0;
    *(bf16x8*)(E + ((size_t)b * D3 + o2 + 1) * D2 + j0) = e1;
    a0[b] = s0; q0[b] = p0; a1[b] = s1; q1[b] = p1;
  }
  __shared__ float red[16][4];
  #pragma unroll
  for (int v = 0; v < 16; v++) {
    float s = (v < 4) ? a0[v] : (v < 8) ? q0[v - 4] : (v < 12) ? a1[v - 8] : q1[v - 12];
    #pragma unroll
    for (int off = 32; off; off >>= 1) s += __shfl_down(s, off, 64);
    if ((tid & 63) == 0) red[v][tid >> 6] = s;
  }
  __syncthreads();
  if (tid < 16) {
    float s = red[tid][0] + red[tid][1] + red[tid][2] + red[tid][3];
    int rr = tid >> 3, u = tid & 7;
    int o = o2 + rr;
    if (u < 4) mu2[u * D3 + o] = s;
    else Pp2[(size_t)(u - 4) * D3 + o] = s;
  }
}

// ---------- K3: gamma2[b] = E_b E_b^T + vn2 I ; Ptot in blocks 0..3 ----------
// Round-5 verified structure: upper-triangular 64x64 tiles (544 blocks),
// 2-buffer LDS prefetch, __syncthreads per tile, mirror-write lower half.
__global__ __launch_bounds__(256, 4) void gamma2_gemm(const __bf16* __restrict__ E,
                                                      const float* __restrict__ vn2v,
                                                      const float* __restrict__ Pp1,
                                                      const float* __restrict__ Pp2,
                                                      const float* __restrict__ g1p,
                                                      const float* __restrict__ g2p,
                                                      float* __restrict__ gamma2,
                                                      float* __restrict__ Ptot) {
  int bid = blockIdx.x, tid = threadIdx.x;
  int wid = tid >> 6, lane = tid & 63;
  int wr = wid >> 1, wc = wid & 1;

  // XCD-pinned decode: 544 blocks (544%8==0), batch b = xcd>>1.
  int xcd = bid & 7, r = bid >> 3;          // r in [0,68)
  int b = xcd >> 1;
  int t = (r << 1) | (xcd & 1);             // [0,136) tile id within batch
  int s = 135 - t;
  int k = (int)((sqrtf((float)(8 * s + 1)) - 1.0f) * 0.5f);
  while ((k + 1) * (k + 2) / 2 <= s) k++;
  while (k * (k + 1) / 2 > s) k--;
  int i = s - k * (k + 1) / 2;
  int tm = 15 - k, tn = 15 - i;

  __shared__ __bf16 As[2][4096], Bs[2][4096];
  char* AsB = (char*)As;
  char* BsB = (char*)Bs;

  const __bf16* Eb = E + (size_t)b * D3 * D2;
  int rb0 = wid >> 1, ks0 = wid & 1;          // region wid
  int rb1 = (wid + 4) >> 1;                   // region wid+4 (same k-half)
  int srow = lane >> 2, skc = lane & 3;
  const __bf16* gA0 = Eb + (size_t)(tm * 64 + rb0 * 16 + srow) * D2 + ks0 * 32 + skc * 8;
  const __bf16* gA1 = Eb + (size_t)(tm * 64 + rb1 * 16 + srow) * D2 + ks0 * 32 + skc * 8;
  const __bf16* gB0 = Eb + (size_t)(tn * 64 + rb0 * 16 + srow) * D2 + ks0 * 32 + skc * 8;
  const __bf16* gB1 = Eb + (size_t)(tn * 64 + rb1 * 16 + srow) * D2 + ks0 * 32 + skc * 8;
  unsigned dst0 = (unsigned)wid * 1024u;          // HW adds lane*16
  unsigned dst1 = dst0 + 4096u;

  int fr = lane & 15, kg = lane >> 4;
  unsigned po = (unsigned)(fr * 64 + kg * 16);
  unsigned aM0 = (unsigned)(wr * 4096) + po;
  unsigned aM1 = aM0 + 2048u;
  unsigned bN0 = (unsigned)(wc * 4096) + po;
  unsigned bN1 = bN0 + 2048u;

  f32x4 acc[2][2] = {};

#define STAGE(bufoff, kelem)                                   \
  {                                                            \
    GLOAD16(gA0 + (kelem), AsB + (bufoff) + dst0);             \
    GLOAD16(gA1 + (kelem), AsB + (bufoff) + dst1);             \
    GLOAD16(gB0 + (kelem), BsB + (bufoff) + dst0);             \
    GLOAD16(gB1 + (kelem), BsB + (bufoff) + dst1);             \
  }

#define COMPUTE(bufoff)                                                         \
  {                                                                             \
    _Pragma("unroll")                                                           \
    for (int ks2 = 0; ks2 < 2; ks2++) {                                         \
      unsigned kso = (unsigned)ks2 << 10;                                       \
      bf16x8 a0 = *(const bf16x8*)(AsB + (bufoff) + aM0 + kso);                 \
      bf16x8 a1 = *(const bf16x8*)(AsB + (bufoff) + aM1 + kso);                 \
      bf16x8 b0 = *(const bf16x8*)(BsB + (bufoff) + bN0 + kso);                 \
      bf16x8 b1 = *(const bf16x8*)(BsB + (bufoff) + bN1 + kso);                 \
      acc[0][0] = __builtin_amdgcn_mfma_f32_16x16x32_bf16(a0, b0, acc[0][0], 0, 0, 0); \
      acc[0][1] = __builtin_amdgcn_mfma_f32_16x16x32_bf16(a0, b1, acc[0][1], 0, 0, 0); \
      acc[1][0] = __builtin_amdgcn_mfma_f32_16x16x32_bf16(a1, b0, acc[1][0], 0, 0, 0); \
      acc[1][1] = __builtin_amdgcn_mfma_f32_16x16x32_bf16(a1, b1, acc[1][1], 0, 0, 0); \
    }                                                                           \
  }

  STAGE(0u, 0);
  __syncthreads();
  unsigned cur = 0;
  #pragma unroll 1
  for (int kt = 0; kt < 31; kt++) {
    unsigned nxt = cur ^ 8192u;
    STAGE(nxt, (kt + 1) * 64);   // prefetch next tile; latency hides under compute
    COMPUTE(cur);
    __syncthreads();
    cur = nxt;
  }
  COMPUTE(cur);
#undef STAGE
#undef COMPUTE

  float c2 = g2p[0];
  // blocks 0..3, wave 0: finalize Ptot[bid] (Pp1 from K1, Pp2 from K2 - both done)
  if (bid < 4 && wid == 0) {
    float s1 = 0.f, s2 = 0.f;
    #pragma unroll
    for (int ii = 0; ii < 32; ii++) s1 += Pp1[(size_t)bid * D2 + lane + ii * 64];
    #pragma unroll
    for (int ii = 0; ii < 16; ii++) s2 += Pp2[(size_t)bid * D3 + lane + ii * 64];
    #pragma unroll
    for (int off = 32; off; off >>= 1) {
      s1 += __shfl_down(s1, off, 64);
      s2 += __shfl_down(s2, off, 64);
    }
    if (lane == 0) Ptot[bid] = g1p[0] * s1 + c2 * s2;
  }

  float vn2 = vn2v[b];
  float* outb = gamma2 + (size_t)b * D3 * D3;
  int row0 = tm * 64 + wr * 32 + kg * 4;
  int col0 = tn * 64 + wc * 32 + fr;
  #pragma unroll
  for (int mi = 0; mi < 2; mi++)
    #pragma unroll
    for (int ni = 0; ni < 2; ni++)
      #pragma unroll
      for (int rg = 0; rg < 4; rg++) {
        int row = row0 + mi * 16 + rg;
        int cc = col0 + ni * 16;
        float v = acc[mi][ni][rg];
        if (row == cc) v += vn2;
        outb[(size_t)row * D3 + cc] = v;
      }
  if (tm != tn) {
    #pragma unroll
    for (int mi = 0; mi < 2; mi++)
      #pragma unroll
      for (int ni = 0; ni < 2; ni++) {
        int cc = col0 + ni * 16;
        int rowb = row0 + mi * 16;
        *(f32x4*)(outb + (size_t)cc * D3 + rowb) = acc[mi][ni];
      }
  }
}

extern "C" void kernel_launch(void* const* d_in, const int* in_sizes, int n_in,
                              void* d_out, int out_size, void* d_ws, size_t ws_size,
                              hipStream_t stream) {
  (void)in_sizes; (void)n_in; (void)out_size; (void)ws_size;
  const float* x    = (const float*)d_in[0];
  const float* bias = (const float*)d_in[1];
  const float* W1   = (const float*)d_in[2];
  const float* W2   = (const float*)d_in[3];
  const float* g1   = (const float*)d_in[4];
  const float* g2   = (const float*)d_in[5];
  float* out = (float*)d_out;

  float* ws     = (float*)d_ws;
  float* musp   = ws;                    // 4*2048
  float* dscale = musp + 4 * D2;         // 4*2048
  float* m2b    = dscale + 4 * D2;       // 4*2048
  float* Pp1    = m2b + 4 * D2;          // 4*2048
  float* Pp2    = Pp1 + 4 * D2;          // 4*1024
  float* vn2v   = Pp2 + 4 * D3;          // 4
  size_t used = (size_t)(4 * 4 * D2 + 4 * D3 + 16) * 4;
  size_t eoff = (used + 255) / 256 * 256;
  __bf16* E = (__bf16*)((char*)d_ws + eoff);   // 4*1024*2048 bf16 = 16 MiB

  float* mu2_out  = out;
  float* gam_out  = out + 4 * D3;
  float* ptot_out = out + 4 * D3 + (size_t)4 * D3 * D3;

  lin1_fused<<<512, 256, 0, stream>>>(x, bias, W1, g1, musp, dscale, m2b, Pp1);
  lin2_prep_kernel<<<516, 256, 0, stream>>>(W2, musp, dscale, m2b, g2, E, mu2_out, Pp2, vn2v);
  gamma2_gemm<<<544, 256, 0, stream>>>(E, vn2v, Pp1, Pp2, g1, g2, gam_out, ptot_out);
}

// Round 8
// 54.546 us; speedup vs baseline: 1.1721x; 1.1102x over previous
//
#include <hip/hip_runtime.h>
#include <hip/hip_bf16.h>
#include <cstdint>

#define SIGMA 0.01f

constexpr int D1 = 3072;
constexpr int D2 = 2048;
constexpr int D3 = 1024;

typedef __bf16 bf16x8 __attribute__((ext_vector_type(8)));
typedef float f32x4 __attribute__((ext_vector_type(4)));

#define GLOAD16(gp, lp) \
  __builtin_amdgcn_global_load_lds((const __attribute__((address_space(1))) void*)(gp), \
                                   (__attribute__((address_space(3))) void*)(lp), 16, 0, 0)

// ---------- K1: bias add + 2x2 avgpool + per-block partial sum(pooled^2) ----------
__global__ void pool_kernel(const float* __restrict__ x, const float* __restrict__ bias,
                            float* __restrict__ pooled, float* __restrict__ Spart) {
  int idx = blockIdx.x * 256 + threadIdx.x;   // [0, 4*3072)
  int b = idx / D1;
  int r = idx % D1;
  int c = r >> 10;
  int oh = (r >> 5) & 31;
  int ow = r & 31;
  int xb = ((b * 3 + c) * 64 + oh * 2) * 64 + ow * 2;
  int bb = (c * 64 + oh * 2) * 64 + ow * 2;
  float v = 0.25f * ((x[xb] + bias[bb]) + (x[xb + 1] + bias[bb + 1]) +
                     (x[xb + 64] + bias[bb + 64]) + (x[xb + 65] + bias[bb + 65]));
  pooled[idx] = v;
  float s = v * v;
  #pragma unroll
  for (int off = 32; off; off >>= 1) s += __shfl_down(s, off, 64);
  __shared__ float wsum[4];
  if ((threadIdx.x & 63) == 0) wsum[threadIdx.x >> 6] = s;
  __syncthreads();
  if (threadIdx.x == 0) Spart[blockIdx.x] = wsum[0] + wsum[1] + wsum[2] + wsum[3];
}

// ---------- K2: mu=pooled@W1^T (+activation moments), 2 rows/block ----------
__global__ void lin1_kernel(const float* __restrict__ pooled, const float* __restrict__ W1,
                            const float* __restrict__ Spart, const float* __restrict__ g1p,
                            float* __restrict__ musp, float* __restrict__ dscale,
                            float* __restrict__ m2b, float* __restrict__ Pp1) {
  int o2 = blockIdx.x << 1, tid = threadIdx.x;
  const float4* w0p = (const float4*)(W1 + (size_t)o2 * D1);
  const float4* w1p = (const float4*)(W1 + (size_t)(o2 + 1) * D1);
  const float4* p4 = (const float4*)pooled;
  float a0[4] = {0,0,0,0}, q0[4] = {0,0,0,0}, a1[4] = {0,0,0,0}, q1[4] = {0,0,0,0};
  #pragma unroll
  for (int it = 0; it < 3; it++) {
    int i4 = tid + it * 256;
    float4 w0 = w0p[i4], w1 = w1p[i4];
    float x0x = fabsf(w0.x), x0y = fabsf(w0.y), x0z = fabsf(w0.z), x0w = fabsf(w0.w);
    float x1x = fabsf(w1.x), x1y = fabsf(w1.y), x1z = fabsf(w1.z), x1w = fabsf(w1.w);
    #pragma unroll
    for (int b = 0; b < 4; b++) {
      float4 p = p4[b * 768 + i4];
      float px = p.x * p.x, py = p.y * p.y, pz = p.z * p.z, pw = p.w * p.w;
      a0[b] += w0.x * p.x + w0.y * p.y + w0.z * p.z + w0.w * p.w;
      q0[b] += x0x * px + x0y * py + x0z * pz + x0w * pw;
      a1[b] += w1.x * p.x + w1.y * p.y + w1.z * p.z + w1.w * p.w;
      q1[b] += x1x * px + x1y * py + x1z * pz + x1w * pw;
    }
  }
  __shared__ float red[16][4];
  #pragma unroll
  for (int v = 0; v < 16; v++) {
    float s = (v < 4) ? a0[v] : (v < 8) ? q0[v - 4] : (v < 12) ? a1[v - 8] : q1[v - 12];
    #pragma unroll
    for (int off = 32; off; off >>= 1) s += __shfl_down(s, off, 64);
    if ((tid & 63) == 0) red[v][tid >> 6] = s;
  }
  __syncthreads();
  if (tid < 16) {
    float s = red[tid][0] + red[tid][1] + red[tid][2] + red[tid][3];
    int rr = tid >> 3, u = tid & 7;
    int o = o2 + rr;
    if (u < 4) {
      int b = u;
      float ss = 0.f;
      #pragma unroll
      for (int i = 0; i < 12; i++) ss += Spart[b * 12 + i];
      float c1 = g1p[0];
      float vn1 = 2.0f * (SIGMA / c1) * (SIGMA / c1) * ss;
      float d = 1.0f / (1.0f + expf(-s));
      float sp = fmaxf(s, 0.f) + log1pf(expf(-fabsf(s)));
      musp[b * D2 + o] = sp;
      dscale[b * D2 + o] = sqrtf(vn1) * d;
      m2b[b * D2 + o] = sp * sp + vn1 * d * d;
    } else {
      Pp1[(size_t)(u - 4) * D2 + o] = s;
    }
  }
}

// ---------- K3: E = bf16(W2*dscale); mu2; Pp2 partials; blocks 512..515: vn2v ----------
__global__ void lin2_prep_kernel(const float* __restrict__ W2, const float* __restrict__ musp,
                                 const float* __restrict__ dscale, const float* __restrict__ m2b,
                                 const float* __restrict__ g2p, __bf16* __restrict__ E,
                                 float* __restrict__ mu2, float* __restrict__ Pp2,
                                 float* __restrict__ vn2v) {
  int tid = threadIdx.x;
  if (blockIdx.x >= 512) {
    int b = blockIdx.x - 512;
    float sm = 0.f;
    #pragma unroll
    for (int i = 0; i < 8; i++) sm += m2b[(size_t)b * D2 + tid + i * 256];
    #pragma unroll
    for (int off = 32; off; off >>= 1) sm += __shfl_down(sm, off, 64);
    __shared__ float red1[4];
    if ((tid & 63) == 0) red1[tid >> 6] = sm;
    __syncthreads();
    if (tid == 0) {
      float c2 = g2p[0];
      vn2v[b] = 2.0f * (SIGMA / c2) * (SIGMA / c2) * (red1[0] + red1[1] + red1[2] + red1[3]);
    }
    return;
  }
  int o2 = blockIdx.x << 1;
  int j0 = tid * 8;
  float w0[8], w1[8];
  *(float4*)&w0[0] = *(const float4*)(W2 + (size_t)o2 * D2 + j0);
  *(float4*)&w0[4] = *(const float4*)(W2 + (size_t)o2 * D2 + j0 + 4);
  *(float4*)&w1[0] = *(const float4*)(W2 + (size_t)(o2 + 1) * D2 + j0);
  *(float4*)&w1[4] = *(const float4*)(W2 + (size_t)(o2 + 1) * D2 + j0 + 4);
  float a0[4], q0[4], a1[4], q1[4];
  #pragma unroll
  for (int b = 0; b < 4; b++) {
    const float* ms = musp + b * D2 + j0;
    const float* dsc = dscale + b * D2 + j0;
    const float* mb = m2b + b * D2 + j0;
    bf16x8 e0, e1;
    float s0 = 0.f, p0 = 0.f, s1 = 0.f, p1 = 0.f;
    #pragma unroll
    for (int jj = 0; jj < 8; jj++) {
      float dv = dsc[jj], mv = ms[jj], bv = mb[jj];
      e0[jj] = (__bf16)(w0[jj] * dv);
      e1[jj] = (__bf16)(w1[jj] * dv);
      s0 += w0[jj] * mv;  p0 += fabsf(w0[jj]) * bv;
      s1 += w1[jj] * mv;  p1 += fabsf(w1[jj]) * bv;
    }
    *(bf16x8*)(E + ((size_t)b * D3 + o2) * D2 + j0) = e0;
    *(bf16x8*)(E + ((size_t)b * D3 + o2 + 1) * D2 + j0) = e1;
    a0[b] = s0; q0[b] = p0; a1[b] = s1; q1[b] = p1;
  }
  __shared__ float red[16][4];
  #pragma unroll
  for (int v = 0; v < 16; v++) {
    float s = (v < 4) ? a0[v] : (v < 8) ? q0[v - 4] : (v < 12) ? a1[v - 8] : q1[v - 12];
    #pragma unroll
    for (int off = 32; off; off >>= 1) s += __shfl_down(s, off, 64);
    if ((tid & 63) == 0) red[v][tid >> 6] = s;
  }
  __syncthreads();
  if (tid < 16) {
    float s = red[tid][0] + red[tid][1] + red[tid][2] + red[tid][3];
    int rr = tid >> 3, u = tid & 7;
    int o = o2 + rr;
    if (u < 4) mu2[u * D3 + o] = s;
    else Pp2[(size_t)(u - 4) * D3 + o] = s;
  }
}

// ---------- K4: gamma2[b] = E_b E_b^T + vn2 I ; Ptot in blocks 0..3 ----------
// Round-5 verified structure: upper-triangular 64x64 tiles (544 blocks),
// 2-buffer LDS prefetch, __syncthreads per tile, mirror-write lower half.
__global__ __launch_bounds__(256, 4) void gamma2_gemm(const __bf16* __restrict__ E,
                                                      const float* __restrict__ vn2v,
                                                      const float* __restrict__ Pp1,
                                                      const float* __restrict__ Pp2,
                                                      const float* __restrict__ g1p,
                                                      const float* __restrict__ g2p,
                                                      float* __restrict__ gamma2,
                                                      float* __restrict__ Ptot) {
  int bid = blockIdx.x, tid = threadIdx.x;
  int wid = tid >> 6, lane = tid & 63;
  int wr = wid >> 1, wc = wid & 1;

  // XCD-pinned decode: 544 blocks (544%8==0), batch b = xcd>>1.
  int xcd = bid & 7, r = bid >> 3;          // r in [0,68)
  int b = xcd >> 1;
  int t = (r << 1) | (xcd & 1);             // [0,136) tile id within batch
  int s = 135 - t;
  int k = (int)((sqrtf((float)(8 * s + 1)) - 1.0f) * 0.5f);
  while ((k + 1) * (k + 2) / 2 <= s) k++;
  while (k * (k + 1) / 2 > s) k--;
  int i = s - k * (k + 1) / 2;
  int tm = 15 - k, tn = 15 - i;

  __shared__ __bf16 As[2][4096], Bs[2][4096];
  char* AsB = (char*)As;
  char* BsB = (char*)Bs;

  const __bf16* Eb = E + (size_t)b * D3 * D2;
  int rb0 = wid >> 1, ks0 = wid & 1;          // region wid
  int rb1 = (wid + 4) >> 1;                   // region wid+4 (same k-half)
  int srow = lane >> 2, skc = lane & 3;
  const __bf16* gA0 = Eb + (size_t)(tm * 64 + rb0 * 16 + srow) * D2 + ks0 * 32 + skc * 8;
  const __bf16* gA1 = Eb + (size_t)(tm * 64 + rb1 * 16 + srow) * D2 + ks0 * 32 + skc * 8;
  const __bf16* gB0 = Eb + (size_t)(tn * 64 + rb0 * 16 + srow) * D2 + ks0 * 32 + skc * 8;
  const __bf16* gB1 = Eb + (size_t)(tn * 64 + rb1 * 16 + srow) * D2 + ks0 * 32 + skc * 8;
  unsigned dst0 = (unsigned)wid * 1024u;          // HW adds lane*16
  unsigned dst1 = dst0 + 4096u;

  int fr = lane & 15, kg = lane >> 4;
  unsigned po = (unsigned)(fr * 64 + kg * 16);
  unsigned aM0 = (unsigned)(wr * 4096) + po;
  unsigned aM1 = aM0 + 2048u;
  unsigned bN0 = (unsigned)(wc * 4096) + po;
  unsigned bN1 = bN0 + 2048u;

  f32x4 acc[2][2] = {};

#define STAGE(bufoff, kelem)                                   \
  {                                                            \
    GLOAD16(gA0 + (kelem), AsB + (bufoff) + dst0);             \
    GLOAD16(gA1 + (kelem), AsB + (bufoff) + dst1);             \
    GLOAD16(gB0 + (kelem), BsB + (bufoff) + dst0);             \
    GLOAD16(gB1 + (kelem), BsB + (bufoff) + dst1);             \
  }

#define COMPUTE(bufoff)                                                         \
  {                                                                             \
    _Pragma("unroll")                                                           \
    for (int ks2 = 0; ks2 < 2; ks2++) {                                         \
      unsigned kso = (unsigned)ks2 << 10;                                       \
      bf16x8 a0 = *(const bf16x8*)(AsB + (bufoff) + aM0 + kso);                 \
      bf16x8 a1 = *(const bf16x8*)(AsB + (bufoff) + aM1 + kso);                 \
      bf16x8 b0 = *(const bf16x8*)(BsB + (bufoff) + bN0 + kso);                 \
      bf16x8 b1 = *(const bf16x8*)(BsB + (bufoff) + bN1 + kso);                 \
      acc[0][0] = __builtin_amdgcn_mfma_f32_16x16x32_bf16(a0, b0, acc[0][0], 0, 0, 0); \
      acc[0][1] = __builtin_amdgcn_mfma_f32_16x16x32_bf16(a0, b1, acc[0][1], 0, 0, 0); \
      acc[1][0] = __builtin_amdgcn_mfma_f32_16x16x32_bf16(a1, b0, acc[1][0], 0, 0, 0); \
      acc[1][1] = __builtin_amdgcn_mfma_f32_16x16x32_bf16(a1, b1, acc[1][1], 0, 0, 0); \
    }                                                                           \
  }

  STAGE(0u, 0);
  __syncthreads();
  unsigned cur = 0;
  #pragma unroll 1
  for (int kt = 0; kt < 31; kt++) {
    unsigned nxt = cur ^ 8192u;
    STAGE(nxt, (kt + 1) * 64);   // prefetch next tile; latency hides under compute
    COMPUTE(cur);
    __syncthreads();
    cur = nxt;
  }
  COMPUTE(cur);
#undef STAGE
#undef COMPUTE

  float c2 = g2p[0];
  // blocks 0..3, wave 0: finalize Ptot[bid] (Pp1 from K2, Pp2 from K3 - both done)
  if (bid < 4 && wid == 0) {
    float s1 = 0.f, s2 = 0.f;
    #pragma unroll
    for (int ii = 0; ii < 32; ii++) s1 += Pp1[(size_t)bid * D2 + lane + ii * 64];
    #pragma unroll
    for (int ii = 0; ii < 16; ii++) s2 += Pp2[(size_t)bid * D3 + lane + ii * 64];
    #pragma unroll
    for (int off = 32; off; off >>= 1) {
      s1 += __shfl_down(s1, off, 64);
      s2 += __shfl_down(s2, off, 64);
    }
    if (lane == 0) Ptot[bid] = g1p[0] * s1 + c2 * s2;
  }

  float vn2 = vn2v[b];
  float* outb = gamma2 + (size_t)b * D3 * D3;
  int row0 = tm * 64 + wr * 32 + kg * 4;
  int col0 = tn * 64 + wc * 32 + fr;
  #pragma unroll
  for (int mi = 0; mi < 2; mi++)
    #pragma unroll
    for (int ni = 0; ni < 2; ni++)
      #pragma unroll
      for (int rg = 0; rg < 4; rg++) {
        int row = row0 + mi * 16 + rg;
        int cc = col0 + ni * 16;
        float v = acc[mi][ni][rg];
        if (row == cc) v += vn2;
        outb[(size_t)row * D3 + cc] = v;
      }
  if (tm != tn) {
    #pragma unroll
    for (int mi = 0; mi < 2; mi++)
      #pragma unroll
      for (int ni = 0; ni < 2; ni++) {
        int cc = col0 + ni * 16;
        int rowb = row0 + mi * 16;
        *(f32x4*)(outb + (size_t)cc * D3 + rowb) = acc[mi][ni];
      }
  }
}

extern "C" void kernel_launch(void* const* d_in, const int* in_sizes, int n_in,
                              void* d_out, int out_size, void* d_ws, size_t ws_size,
                              hipStream_t stream) {
  (void)in_sizes; (void)n_in; (void)out_size; (void)ws_size;
  const float* x    = (const float*)d_in[0];
  const float* bias = (const float*)d_in[1];
  const float* W1   = (const float*)d_in[2];
  const float* W2   = (const float*)d_in[3];
  const float* g1   = (const float*)d_in[4];
  const float* g2   = (const float*)d_in[5];
  float* out = (float*)d_out;

  float* ws     = (float*)d_ws;
  float* pooled = ws;                    // 4*3072
  float* musp   = pooled + 4 * D1;       // 4*2048
  float* dscale = musp + 4 * D2;         // 4*2048
  float* m2b    = dscale + 4 * D2;       // 4*2048
  float* Pp1    = m2b + 4 * D2;          // 4*2048
  float* Pp2    = Pp1 + 4 * D2;          // 4*1024
  float* Spart  = Pp2 + 4 * D3;          // 48
  float* vn2v   = Spart + 48;            // 4
  size_t used = (size_t)(4 * D1 + 4 * 4 * D2 + 4 * D3 + 64) * 4;
  size_t eoff = (used + 255) / 256 * 256;
  __bf16* E = (__bf16*)((char*)d_ws + eoff);   // 4*1024*2048 bf16 = 16 MiB

  float* mu2_out  = out;
  float* gam_out  = out + 4 * D3;
  float* ptot_out = out + 4 * D3 + (size_t)4 * D3 * D3;

  pool_kernel<<<48, 256, 0, stream>>>(x, bias, pooled, Spart);
  lin1_kernel<<<1024, 256, 0, stream>>>(pooled, W1, Spart, g1, musp, dscale, m2b, Pp1);
  lin2_prep_kernel<<<516, 256, 0, stream>>>(W2, musp, dscale, m2b, g2, E, mu2_out, Pp2, vn2v);
  gamma2_gemm<<<544, 256, 0, stream>>>(E, vn2v, Pp1, Pp2, g1, g2, gam_out, ptot_out);
}

// Round 11
// 53.188 us; speedup vs baseline: 1.2020x; 1.0255x over previous
//
#include <hip/hip_runtime.h>
#include <hip/hip_bf16.h>
#include <cstdint>

#define SIGMA 0.01f

constexpr int D1 = 3072;
constexpr int D2 = 2048;
constexpr int D3 = 1024;

typedef __bf16 bf16x8 __attribute__((ext_vector_type(8)));
typedef float f32x4 __attribute__((ext_vector_type(4)));

#define GLOAD16(gp, lp) \
  __builtin_amdgcn_global_load_lds((const __attribute__((address_space(1))) void*)(gp), \
                                   (__attribute__((address_space(3))) void*)(lp), 16, 0, 0)

// ---------- K1: bias add + 2x2 avgpool + per-block partial sum(pooled^2) ----------
__global__ void pool_kernel(const float* __restrict__ x, const float* __restrict__ bias,
                            float* __restrict__ pooled, float* __restrict__ Spart) {
  int idx = blockIdx.x * 256 + threadIdx.x;   // [0, 4*3072)
  int b = idx / D1;
  int r = idx % D1;
  int c = r >> 10;
  int oh = (r >> 5) & 31;
  int ow = r & 31;
  int xb = ((b * 3 + c) * 64 + oh * 2) * 64 + ow * 2;
  int bb = (c * 64 + oh * 2) * 64 + ow * 2;
  float v = 0.25f * ((x[xb] + bias[bb]) + (x[xb + 1] + bias[bb + 1]) +
                     (x[xb + 64] + bias[bb + 64]) + (x[xb + 65] + bias[bb + 65]));
  pooled[idx] = v;
  float s = v * v;
  #pragma unroll
  for (int off = 32; off; off >>= 1) s += __shfl_down(s, off, 64);
  __shared__ float wsum[4];
  if ((threadIdx.x & 63) == 0) wsum[threadIdx.x >> 6] = s;
  __syncthreads();
  if (threadIdx.x == 0) Spart[blockIdx.x] = wsum[0] + wsum[1] + wsum[2] + wsum[3];
}

// ---------- K2: mu=pooled@W1^T (+activation moments), 2 rows/block ----------
__global__ void lin1_kernel(const float* __restrict__ pooled, const float* __restrict__ W1,
                            const float* __restrict__ Spart, const float* __restrict__ g1p,
                            float* __restrict__ musp, float* __restrict__ dscale,
                            float* __restrict__ m2b, float* __restrict__ Pp1) {
  int o2 = blockIdx.x << 1, tid = threadIdx.x;
  const float4* w0p = (const float4*)(W1 + (size_t)o2 * D1);
  const float4* w1p = (const float4*)(W1 + (size_t)(o2 + 1) * D1);
  const float4* p4 = (const float4*)pooled;
  float a0[4] = {0,0,0,0}, q0[4] = {0,0,0,0}, a1[4] = {0,0,0,0}, q1[4] = {0,0,0,0};
  #pragma unroll
  for (int it = 0; it < 3; it++) {
    int i4 = tid + it * 256;
    float4 w0 = w0p[i4], w1 = w1p[i4];
    float x0x = fabsf(w0.x), x0y = fabsf(w0.y), x0z = fabsf(w0.z), x0w = fabsf(w0.w);
    float x1x = fabsf(w1.x), x1y = fabsf(w1.y), x1z = fabsf(w1.z), x1w = fabsf(w1.w);
    #pragma unroll
    for (int b = 0; b < 4; b++) {
      float4 p = p4[b * 768 + i4];
      float px = p.x * p.x, py = p.y * p.y, pz = p.z * p.z, pw = p.w * p.w;
      a0[b] += w0.x * p.x + w0.y * p.y + w0.z * p.z + w0.w * p.w;
      q0[b] += x0x * px + x0y * py + x0z * pz + x0w * pw;
      a1[b] += w1.x * p.x + w1.y * p.y + w1.z * p.z + w1.w * p.w;
      q1[b] += x1x * px + x1y * py + x1z * pz + x1w * pw;
    }
  }
  __shared__ float red[16][4];
  #pragma unroll
  for (int v = 0; v < 16; v++) {
    float s = (v < 4) ? a0[v] : (v < 8) ? q0[v - 4] : (v < 12) ? a1[v - 8] : q1[v - 12];
    #pragma unroll
    for (int off = 32; off; off >>= 1) s += __shfl_down(s, off, 64);
    if ((tid & 63) == 0) red[v][tid >> 6] = s;
  }
  __syncthreads();
  if (tid < 16) {
    float s = red[tid][0] + red[tid][1] + red[tid][2] + red[tid][3];
    int rr = tid >> 3, u = tid & 7;
    int o = o2 + rr;
    if (u < 4) {
      int b = u;
      float ss = 0.f;
      #pragma unroll
      for (int i = 0; i < 12; i++) ss += Spart[b * 12 + i];
      float c1 = g1p[0];
      float vn1 = 2.0f * (SIGMA / c1) * (SIGMA / c1) * ss;
      float d = 1.0f / (1.0f + expf(-s));
      float sp = fmaxf(s, 0.f) + log1pf(expf(-fabsf(s)));
      musp[b * D2 + o] = sp;
      dscale[b * D2 + o] = sqrtf(vn1) * d;
      m2b[b * D2 + o] = sp * sp + vn1 * d * d;
    } else {
      Pp1[(size_t)(u - 4) * D2 + o] = s;
    }
  }
}

// ---------- K3: E = bf16(W2*dscale); mu2; Pp2 partials; blocks 512..515: vn2v ----------
__global__ void lin2_prep_kernel(const float* __restrict__ W2, const float* __restrict__ musp,
                                 const float* __restrict__ dscale, const float* __restrict__ m2b,
                                 const float* __restrict__ g2p, __bf16* __restrict__ E,
                                 float* __restrict__ mu2, float* __restrict__ Pp2,
                                 float* __restrict__ vn2v) {
  int tid = threadIdx.x;
  if (blockIdx.x >= 512) {
    int b = blockIdx.x - 512;
    float sm = 0.f;
    #pragma unroll
    for (int i = 0; i < 8; i++) sm += m2b[(size_t)b * D2 + tid + i * 256];
    #pragma unroll
    for (int off = 32; off; off >>= 1) sm += __shfl_down(sm, off, 64);
    __shared__ float red1[4];
    if ((tid & 63) == 0) red1[tid >> 6] = sm;
    __syncthreads();
    if (tid == 0) {
      float c2 = g2p[0];
      vn2v[b] = 2.0f * (SIGMA / c2) * (SIGMA / c2) * (red1[0] + red1[1] + red1[2] + red1[3]);
    }
    return;
  }
  int o2 = blockIdx.x << 1;
  int j0 = tid * 8;
  float w0[8], w1[8];
  *(float4*)&w0[0] = *(const float4*)(W2 + (size_t)o2 * D2 + j0);
  *(float4*)&w0[4] = *(const float4*)(W2 + (size_t)o2 * D2 + j0 + 4);
  *(float4*)&w1[0] = *(const float4*)(W2 + (size_t)(o2 + 1) * D2 + j0);
  *(float4*)&w1[4] = *(const float4*)(W2 + (size_t)(o2 + 1) * D2 + j0 + 4);
  float a0[4], q0[4], a1[4], q1[4];
  #pragma unroll
  for (int b = 0; b < 4; b++) {
    const float* ms = musp + b * D2 + j0;
    const float* dsc = dscale + b * D2 + j0;
    const float* mb = m2b + b * D2 + j0;
    bf16x8 e0, e1;
    float s0 = 0.f, p0 = 0.f, s1 = 0.f, p1 = 0.f;
    #pragma unroll
    for (int jj = 0; jj < 8; jj++) {
      float dv = dsc[jj], mv = ms[jj], bv = mb[jj];
      e0[jj] = (__bf16)(w0[jj] * dv);
      e1[jj] = (__bf16)(w1[jj] * dv);
      s0 += w0[jj] * mv;  p0 += fabsf(w0[jj]) * bv;
      s1 += w1[jj] * mv;  p1 += fabsf(w1[jj]) * bv;
    }
    *(bf16x8*)(E + ((size_t)b * D3 + o2) * D2 + j0) = e0;
    *(bf16x8*)(E + ((size_t)b * D3 + o2 + 1) * D2 + j0) = e1;
    a0[b] = s0; q0[b] = p0; a1[b] = s1; q1[b] = p1;
  }
  __shared__ float red[16][4];
  #pragma unroll
  for (int v = 0; v < 16; v++) {
    float s = (v < 4) ? a0[v] : (v < 8) ? q0[v - 4] : (v < 12) ? a1[v - 8] : q1[v - 12];
    #pragma unroll
    for (int off = 32; off; off >>= 1) s += __shfl_down(s, off, 64);
    if ((tid & 63) == 0) red[v][tid >> 6] = s;
  }
  __syncthreads();
  if (tid < 16) {
    float s = red[tid][0] + red[tid][1] + red[tid][2] + red[tid][3];
    int rr = tid >> 3, u = tid & 7;
    int o = o2 + rr;
    if (u < 4) mu2[u * D3 + o] = s;
    else Pp2[(size_t)(u - 4) * D3 + o] = s;
  }
}

// ---------- K4: gamma2[b] = E_b E_b^T + vn2 I ; Ptot in blocks 0..3 ----------
// R8 verified structure + (a) non-temporal output stores (keep E_b resident in
// the pinned XCD L2 -> panel re-reads stay L2 hits), (b) diagonal tiles skip
// B staging and read both operands from As (block-uniform alias).
__global__ __launch_bounds__(256, 4) void gamma2_gemm(const __bf16* __restrict__ E,
                                                      const float* __restrict__ vn2v,
                                                      const float* __restrict__ Pp1,
                                                      const float* __restrict__ Pp2,
                                                      const float* __restrict__ g1p,
                                                      const float* __restrict__ g2p,
                                                      float* __restrict__ gamma2,
                                                      float* __restrict__ Ptot) {
  int bid = blockIdx.x, tid = threadIdx.x;
  int wid = tid >> 6, lane = tid & 63;
  int wr = wid >> 1, wc = wid & 1;

  // XCD-pinned decode: 544 blocks (544%8==0), batch b = xcd>>1.
  int xcd = bid & 7, r = bid >> 3;          // r in [0,68)
  int b = xcd >> 1;
  int t = (r << 1) | (xcd & 1);             // [0,136) tile id within batch
  int s = 135 - t;
  int k = (int)((sqrtf((float)(8 * s + 1)) - 1.0f) * 0.5f);
  while ((k + 1) * (k + 2) / 2 <= s) k++;
  while (k * (k + 1) / 2 > s) k--;
  int i = s - k * (k + 1) / 2;
  int tm = 15 - k, tn = 15 - i;
  bool diag = (tm == tn);

  __shared__ __bf16 As[2][4096], Bs[2][4096];
  char* AsB = (char*)As;
  char* BsB = diag ? AsB : (char*)Bs;       // diagonal tiles: B operand = A tile

  const __bf16* Eb = E + (size_t)b * D3 * D2;
  int rb0 = wid >> 1, ks0 = wid & 1;          // region wid
  int rb1 = (wid + 4) >> 1;                   // region wid+4 (same k-half)
  int srow = lane >> 2, skc = lane & 3;
  const __bf16* gA0 = Eb + (size_t)(tm * 64 + rb0 * 16 + srow) * D2 + ks0 * 32 + skc * 8;
  const __bf16* gA1 = Eb + (size_t)(tm * 64 + rb1 * 16 + srow) * D2 + ks0 * 32 + skc * 8;
  const __bf16* gB0 = Eb + (size_t)(tn * 64 + rb0 * 16 + srow) * D2 + ks0 * 32 + skc * 8;
  const __bf16* gB1 = Eb + (size_t)(tn * 64 + rb1 * 16 + srow) * D2 + ks0 * 32 + skc * 8;
  unsigned dst0 = (unsigned)wid * 1024u;          // HW adds lane*16
  unsigned dst1 = dst0 + 4096u;

  int fr = lane & 15, kg = lane >> 4;
  unsigned po = (unsigned)(fr * 64 + kg * 16);
  unsigned aM0 = (unsigned)(wr * 4096) + po;
  unsigned aM1 = aM0 + 2048u;
  unsigned bN0 = (unsigned)(wc * 4096) + po;
  unsigned bN1 = bN0 + 2048u;

  f32x4 acc[2][2] = {};

#define STAGE(bufoff, kelem)                                   \
  {                                                            \
    GLOAD16(gA0 + (kelem), AsB + (bufoff) + dst0);             \
    GLOAD16(gA1 + (kelem), AsB + (bufoff) + dst1);             \
    if (!diag) {                                               \
      GLOAD16(gB0 + (kelem), BsB + (bufoff) + dst0);           \
      GLOAD16(gB1 + (kelem), BsB + (bufoff) + dst1);           \
    }                                                          \
  }

#define COMPUTE(bufoff)                                                         \
  {                                                                             \
    _Pragma("unroll")                                                           \
    for (int ks2 = 0; ks2 < 2; ks2++) {                                         \
      unsigned kso = (unsigned)ks2 << 10;                                       \
      bf16x8 a0 = *(const bf16x8*)(AsB + (bufoff) + aM0 + kso);                 \
      bf16x8 a1 = *(const bf16x8*)(AsB + (bufoff) + aM1 + kso);                 \
      bf16x8 b0 = *(const bf16x8*)(BsB + (bufoff) + bN0 + kso);                 \
      bf16x8 b1 = *(const bf16x8*)(BsB + (bufoff) + bN1 + kso);                 \
      acc[0][0] = __builtin_amdgcn_mfma_f32_16x16x32_bf16(a0, b0, acc[0][0], 0, 0, 0); \
      acc[0][1] = __builtin_amdgcn_mfma_f32_16x16x32_bf16(a0, b1, acc[0][1], 0, 0, 0); \
      acc[1][0] = __builtin_amdgcn_mfma_f32_16x16x32_bf16(a1, b0, acc[1][0], 0, 0, 0); \
      acc[1][1] = __builtin_amdgcn_mfma_f32_16x16x32_bf16(a1, b1, acc[1][1], 0, 0, 0); \
    }                                                                           \
  }

  STAGE(0u, 0);
  __syncthreads();
  unsigned cur = 0;
  #pragma unroll 1
  for (int kt = 0; kt < 31; kt++) {
    unsigned nxt = cur ^ 8192u;
    STAGE(nxt, (kt + 1) * 64);   // prefetch next tile; latency hides under compute
    COMPUTE(cur);
    __syncthreads();
    cur = nxt;
  }
  COMPUTE(cur);
#undef STAGE
#undef COMPUTE

  float c2 = g2p[0];
  // blocks 0..3, wave 0: finalize Ptot[bid] (Pp1 from K2, Pp2 from K3 - both done)
  if (bid < 4 && wid == 0) {
    float s1 = 0.f, s2 = 0.f;
    #pragma unroll
    for (int ii = 0; ii < 32; ii++) s1 += Pp1[(size_t)bid * D2 + lane + ii * 64];
    #pragma unroll
    for (int ii = 0; ii < 16; ii++) s2 += Pp2[(size_t)bid * D3 + lane + ii * 64];
    #pragma unroll
    for (int off = 32; off; off >>= 1) {
      s1 += __shfl_down(s1, off, 64);
      s2 += __shfl_down(s2, off, 64);
    }
    if (lane == 0) Ptot[bid] = g1p[0] * s1 + c2 * s2;
  }

  float vn2 = vn2v[b];
  float* outb = gamma2 + (size_t)b * D3 * D3;
  int row0 = tm * 64 + wr * 32 + kg * 4;
  int col0 = tn * 64 + wc * 32 + fr;
  #pragma unroll
  for (int mi = 0; mi < 2; mi++)
    #pragma unroll
    for (int ni = 0; ni < 2; ni++)
      #pragma unroll
      for (int rg = 0; rg < 4; rg++) {
        int row = row0 + mi * 16 + rg;
        int cc = col0 + ni * 16;
        float v = acc[mi][ni][rg];
        if (row == cc) v += vn2;
        __builtin_nontemporal_store(v, outb + (size_t)row * D3 + cc);
      }
  if (!diag) {
    #pragma unroll
    for (int mi = 0; mi < 2; mi++)
      #pragma unroll
      for (int ni = 0; ni < 2; ni++) {
        int cc = col0 + ni * 16;
        int rowb = row0 + mi * 16;
        __builtin_nontemporal_store(acc[mi][ni], (f32x4*)(outb + (size_t)cc * D3 + rowb));
      }
  }
}

extern "C" void kernel_launch(void* const* d_in, const int* in_sizes, int n_in,
                              void* d_out, int out_size, void* d_ws, size_t ws_size,
                              hipStream_t stream) {
  (void)in_sizes; (void)n_in; (void)out_size; (void)ws_size;
  const float* x    = (const float*)d_in[0];
  const float* bias = (const float*)d_in[1];
  const float* W1   = (const float*)d_in[2];
  const float* W2   = (const float*)d_in[3];
  const float* g1   = (const float*)d_in[4];
  const float* g2   = (const float*)d_in[5];
  float* out = (float*)d_out;

  float* ws     = (float*)d_ws;
  float* pooled = ws;                    // 4*3072
  float* musp   = pooled + 4 * D1;       // 4*2048
  float* dscale = musp + 4 * D2;         // 4*2048
  float* m2b    = dscale + 4 * D2;       // 4*2048
  float* Pp1    = m2b + 4 * D2;          // 4*2048
  float* Pp2    = Pp1 + 4 * D2;          // 4*1024
  float* Spart  = Pp2 + 4 * D3;          // 48
  float* vn2v   = Spart + 48;            // 4
  size_t used = (size_t)(4 * D1 + 4 * 4 * D2 + 4 * D3 + 64) * 4;
  size_t eoff = (used + 255) / 256 * 256;
  __bf16* E = (__bf16*)((char*)d_ws + eoff);   // 4*1024*2048 bf16 = 16 MiB

  float* mu2_out  = out;
  float* gam_out  = out + 4 * D3;
  float* ptot_out = out + 4 * D3 + (size_t)4 * D3 * D3;

  pool_kernel<<<48, 256, 0, stream>>>(x, bias, pooled, Spart);
  lin1_kernel<<<1024, 256, 0, stream>>>(pooled, W1, Spart, g1, musp, dscale, m2b, Pp1);
  lin2_prep_kernel<<<516, 256, 0, stream>>>(W2, musp, dscale, m2b, g2, E, mu2_out, Pp2, vn2v);
  gamma2_gemm<<<544, 256, 0, stream>>>(E, vn2v, Pp1, Pp2, g1, g2, gam_out, ptot_out);
}